// Round 17
// baseline (247.456 us; speedup 1.0000x reference)
//
#include <hip/hip_runtime.h>
#include <hip/hip_bf16.h>
#include <stdint.h>

#define IN_F 4096
#define OUT_F 4096
#define NBKT 256
#define SBLOCKS 410          // 410 * 8192 = 3,358,720 >= NNZ
#define REC_PER_SB 8192
#define SMAX 14336u          // per-bucket cap: mean 13107, sigma 114, +10.8 sigma
#define THRESH 0.01f
#define ABL_LOOP 3

typedef unsigned int u32;
typedef unsigned short u16;
typedef unsigned char u8;
typedef __attribute__((ext_vector_type(8))) short short8;   // 8 bf16 = 4 VGPR
typedef __attribute__((ext_vector_type(4))) float f32x4;

// ws layout — offsets DERIVED, 256B-padded
static constexpr size_t pad256(size_t x) { return (x + 255u) & ~(size_t)255u; }
static constexpr size_t WS_XB   = 0;                                           // u16 xB[512][64][8]
static constexpr size_t WS_CUR  = pad256(WS_XB + (size_t)512 * 64 * 8 * 2);    // u32 gcursor[256]
static constexpr size_t WS_BINS = pad256(WS_CUR + (size_t)NBKT * 4);           // u32 sortb[256][SMAX]
static constexpr size_t WS_SCR  = pad256(WS_BINS + (size_t)NBKT * SMAX * 4);   // float scr[256][1024]
static constexpr size_t WS_NEEDED = WS_SCR + (size_t)NBKT * 1024 * 4;

static __device__ __forceinline__ u16 f2bf(float v) {
  __hip_bfloat16 h = __float2bfloat16(v);
  return *reinterpret_cast<u16*>(&h);
}

__global__ __launch_bounds__(256) void k_init(u32* __restrict__ gcursor) {
  gcursor[threadIdx.x] = 0u;
}

// ==== REAL PIPELINE: byte-identical to round-11 champion (57.1 us) ====
__global__ __launch_bounds__(1024) void k_scatter(const int* __restrict__ rows,
                                                  const int* __restrict__ cols,
                                                  const float* __restrict__ vals, u32 nnz,
                                                  const float* __restrict__ x,
                                                  u16* __restrict__ xB,
                                                  u32* __restrict__ gcursor,
                                                  u32* __restrict__ sortb) {
  __shared__ u32 cnt[NBKT];
  __shared__ u32 pref[NBKT + 1];
  __shared__ u32 gbase[NBKT];
  __shared__ u32 srt[REC_PER_SB];   // 32 KB
  __shared__ u8 srtb[REC_PER_SB];   // 8 KB
  const int tid = threadIdx.x;
  const int lane = tid & 63;
  const int wid = tid >> 6;

  if (blockIdx.x < 32) {
    const int g = blockIdx.x * 1024 + tid;
    const int b = g & 63;
    const int kg = g >> 6;
    const float* src = x + (size_t)b * IN_F + kg * 8;
    const f32x4 a0 = *reinterpret_cast<const f32x4*>(src);
    const f32x4 a1 = *reinterpret_cast<const f32x4*>(src + 4);
    short8 o;
#pragma unroll
    for (int e = 0; e < 4; ++e) {
      float v = a0[e]; v = (v > THRESH) ? v : 0.0f; o[e] = (short)f2bf(v);
    }
#pragma unroll
    for (int e = 0; e < 4; ++e) {
      float v = a1[e]; v = (v > THRESH) ? v : 0.0f; o[4 + e] = (short)f2bf(v);
    }
    *reinterpret_cast<short8*>(xB + ((size_t)kg * 64 + b) * 8) = o;
  }

  if (tid < NBKT) cnt[tid] = 0;
  __syncthreads();
  const u32 base_i = blockIdx.x * (u32)REC_PER_SB;
  u32 rec[8], bkt[8], rk[8];
#pragma unroll
  for (int j = 0; j < 8; ++j) {
    const u32 i = base_i + (u32)j * 1024u + tid;
    bkt[j] = 0xffffffffu;
    if (i < nnz) {
      const u32 r = (u32)rows[i] & 4095u;
      const u32 c = (u32)cols[i] & 4095u;
      rec[j] = (c << 20) | ((r & 15u) << 16) | (u32)f2bf(vals[i]);
      bkt[j] = r >> 4;
      rk[j] = atomicAdd(&cnt[bkt[j]], 1u);
    }
  }
  __syncthreads();
  if (wid == 0) {
    u32 a[4]; u32 s = 0;
#pragma unroll
    for (int j = 0; j < 4; ++j) { a[j] = cnt[lane * 4 + j]; s += a[j]; }
    u32 xx = s;
#pragma unroll
    for (int d = 1; d < 64; d <<= 1) {
      const u32 y = (u32)__shfl_up((int)xx, d, 64);
      if (lane >= d) xx += y;
    }
    u32 e = xx - s;
#pragma unroll
    for (int j = 0; j < 4; ++j) { pref[lane * 4 + j] = e; e += a[j]; }
    if (lane == 63) pref[NBKT] = e;
  }
  __syncthreads();
#pragma unroll
  for (int j = 0; j < 8; ++j)
    if (bkt[j] != 0xffffffffu) {
      const u32 pos = pref[bkt[j]] + rk[j];
      srt[pos] = rec[j];
      srtb[pos] = (u8)bkt[j];
    }
  if (tid < NBKT) {
    const u32 len = pref[tid + 1] - pref[tid];
    gbase[tid] = len ? atomicAdd(&gcursor[tid], len) : 0u;
  }
  __syncthreads();
  const u32 tot = pref[NBKT];
#pragma unroll
  for (int j = 0; j < 8; ++j) {
    const u32 i = (u32)j * 1024u + tid;
    if (i < tot) {
      const u32 t = srtb[i];
      const u32 off = gbase[t] + (i - pref[t]);
      if (off < SMAX) sortb[(size_t)t * SMAX + off] = srt[i];
    }
  }
}

__global__ __launch_bounds__(1024, 1) void k_accum(const u32* __restrict__ sortb,
                                                   const u32* __restrict__ ntot,
                                                   const u16* __restrict__ xB,
                                                   const float* __restrict__ bias,
                                                   float* __restrict__ out) {
  __shared__ float W[16 * 1024];
  const int tid = threadIdx.x;
  const int lane = tid & 63;
  const int w = tid >> 6;
  const u32 t = blockIdx.x;
  u32 n = ntot[t];
  if (n > SMAX) n = SMAX;
  const u32* bin = sortb + (size_t)t * SMAX;
  u32 rec[14];
#pragma unroll
  for (int j = 0; j < 14; ++j) {
    const u32 i = (u32)j * 1024u + tid;
    rec[j] = (i < n) ? bin[i] : 0u;
  }
  const f32x4 zv = {0.f, 0.f, 0.f, 0.f};
  f32x4 acc0 = zv, acc1 = zv, acc2 = zv, acc3 = zv;
  const int row = lane & 15;
  const int e8 = (lane >> 4) * 8;

  for (int q = 0; q < 4; ++q) {
    __syncthreads();
#pragma unroll
    for (int j = 0; j < 4; ++j)
      *reinterpret_cast<f32x4*>(&W[j * 4096 + tid * 4]) = zv;
    __syncthreads();
#pragma unroll
    for (int j = 0; j < 14; ++j) {
      const u32 i = (u32)j * 1024u + tid;
      if (i < n) {
        const u32 rc = rec[j];
        if ((rc >> 30) == (u32)q) {
          const u32 rl = (rc >> 16) & 15u;
          const u32 cl = ((rc >> 20) & 1023u) ^ ((rl & 7u) << 3);
          __hip_atomic_fetch_add(&W[rl * 1024u + cl], __uint_as_float(rc << 16),
                                 __ATOMIC_RELAXED, __HIP_MEMORY_SCOPE_WORKGROUP);
        }
      }
    }
    __syncthreads();
#pragma unroll
    for (int s = 0; s < 2; ++s) {
      const int klb = w * 64 + s * 32 + e8;
      const int sw = klb ^ ((row & 7) << 3);
      const f32x4 wa = *reinterpret_cast<const f32x4*>(&W[row * 1024 + sw]);
      const f32x4 wb = *reinterpret_cast<const f32x4*>(&W[row * 1024 + (sw + 4)]);
      short8 af;
#pragma unroll
      for (int e = 0; e < 4; ++e) af[e] = (short)f2bf(wa[e]);
#pragma unroll
      for (int e = 0; e < 4; ++e) af[4 + e] = (short)f2bf(wb[e]);
      const int kabs = q * 1024 + klb;
      const u16* bp = xB + (size_t)(kabs >> 3) * 512 + (u32)row * 8;
      const short8 b0 = *reinterpret_cast<const short8*>(bp);
      const short8 b1 = *reinterpret_cast<const short8*>(bp + 128);
      const short8 b2 = *reinterpret_cast<const short8*>(bp + 256);
      const short8 b3 = *reinterpret_cast<const short8*>(bp + 384);
      acc0 = __builtin_amdgcn_mfma_f32_16x16x32_bf16(af, b0, acc0, 0, 0, 0);
      acc1 = __builtin_amdgcn_mfma_f32_16x16x32_bf16(af, b1, acc1, 0, 0, 0);
      acc2 = __builtin_amdgcn_mfma_f32_16x16x32_bf16(af, b2, acc2, 0, 0, 0);
      acc3 = __builtin_amdgcn_mfma_f32_16x16x32_bf16(af, b3, acc3, 0, 0, 0);
    }
  }
  __syncthreads();
  {
    const int ccol = lane & 15;
    const int rb = (lane >> 4) * 4;
#pragma unroll
    for (int qq = 0; qq < 4; ++qq) W[((w * 4 + 0) * 16 + rb + qq) * 16 + ccol] = acc0[qq];
#pragma unroll
    for (int qq = 0; qq < 4; ++qq) W[((w * 4 + 1) * 16 + rb + qq) * 16 + ccol] = acc1[qq];
#pragma unroll
    for (int qq = 0; qq < 4; ++qq) W[((w * 4 + 2) * 16 + rb + qq) * 16 + ccol] = acc2[qq];
#pragma unroll
    for (int qq = 0; qq < 4; ++qq) W[((w * 4 + 3) * 16 + rb + qq) * 16 + ccol] = acc3[qq];
  }
  __syncthreads();
  const int rl = tid & 15;
  const int b = tid >> 4;
  float sum = bias[t * 16u + rl];
#pragma unroll
  for (int w2 = 0; w2 < 16; ++w2)
    sum += W[((w2 * 4 + (b >> 4)) * 16 + rl) * 16 + (b & 15)];
  out[(size_t)b * OUT_F + t * 16u + rl] = sum;
}

// ==== ABLATION VARIANTS (measurement only; write to ws scratch) ====
// MODE 0: full body. MODE 1: no ds_add densify. MODE 2: no MFMA/B-loads.
// MODE 3: record preload only. Each loops x3 to rank above harness fills in top-5.
template <int MODE>
__global__ __launch_bounds__(1024, 1) void k_abl(const u32* __restrict__ sortb,
                                                 const u32* __restrict__ ntot,
                                                 const u16* __restrict__ xB,
                                                 float* __restrict__ scr) {
  __shared__ float W[16 * 1024];
  const int tid = threadIdx.x;
  const int lane = tid & 63;
  const int w = tid >> 6;
  const u32 t = blockIdx.x;
  u32 n = ntot[t];
  if (n > SMAX) n = SMAX;
  const u32* bin = sortb + (size_t)t * SMAX;
  const f32x4 zv = {0.f, 0.f, 0.f, 0.f};
  f32x4 acc0 = zv, acc1 = zv, acc2 = zv, acc3 = zv;
  const int row = lane & 15;
  const int e8 = (lane >> 4) * 8;
  float sink = 0.f;

  for (int it = 0; it < ABL_LOOP; ++it) {
    asm volatile("" ::: "memory");   // force full re-execution per iteration
    u32 rec[14];
#pragma unroll
    for (int j = 0; j < 14; ++j) {
      const u32 i = (u32)j * 1024u + tid;
      rec[j] = (i < n) ? bin[i] : 0u;
    }
#pragma unroll
    for (int j = 0; j < 14; ++j) asm volatile("" :: "v"(rec[j]));  // rule #17 keep-alive

    if constexpr (MODE == 3) continue;   // preload-only (uniform control flow)

    for (int q = 0; q < 4; ++q) {
      __syncthreads();
#pragma unroll
      for (int j = 0; j < 4; ++j)
        *reinterpret_cast<f32x4*>(&W[j * 4096 + tid * 4]) = zv;
      __syncthreads();
      if constexpr (MODE != 1) {
#pragma unroll
        for (int j = 0; j < 14; ++j) {
          const u32 i = (u32)j * 1024u + tid;
          if (i < n) {
            const u32 rc = rec[j];
            if ((rc >> 30) == (u32)q) {
              const u32 rl = (rc >> 16) & 15u;
              const u32 cl = ((rc >> 20) & 1023u) ^ ((rl & 7u) << 3);
              __hip_atomic_fetch_add(&W[rl * 1024u + cl], __uint_as_float(rc << 16),
                                     __ATOMIC_RELAXED, __HIP_MEMORY_SCOPE_WORKGROUP);
            }
          }
        }
      }
      __syncthreads();
      if constexpr (MODE != 2) {
#pragma unroll
        for (int s = 0; s < 2; ++s) {
          const int klb = w * 64 + s * 32 + e8;
          const int sw = klb ^ ((row & 7) << 3);
          const f32x4 wa = *reinterpret_cast<const f32x4*>(&W[row * 1024 + sw]);
          const f32x4 wb = *reinterpret_cast<const f32x4*>(&W[row * 1024 + (sw + 4)]);
          short8 af;
#pragma unroll
          for (int e = 0; e < 4; ++e) af[e] = (short)f2bf(wa[e]);
#pragma unroll
          for (int e = 0; e < 4; ++e) af[4 + e] = (short)f2bf(wb[e]);
          const int kabs = q * 1024 + klb;
          const u16* bp = xB + (size_t)(kabs >> 3) * 512 + (u32)row * 8;
          const short8 b0 = *reinterpret_cast<const short8*>(bp);
          const short8 b1 = *reinterpret_cast<const short8*>(bp + 128);
          const short8 b2 = *reinterpret_cast<const short8*>(bp + 256);
          const short8 b3 = *reinterpret_cast<const short8*>(bp + 384);
          acc0 = __builtin_amdgcn_mfma_f32_16x16x32_bf16(af, b0, acc0, 0, 0, 0);
          acc1 = __builtin_amdgcn_mfma_f32_16x16x32_bf16(af, b1, acc1, 0, 0, 0);
          acc2 = __builtin_amdgcn_mfma_f32_16x16x32_bf16(af, b2, acc2, 0, 0, 0);
          acc3 = __builtin_amdgcn_mfma_f32_16x16x32_bf16(af, b3, acc3, 0, 0, 0);
        }
      } else {
        sink += W[(u32)(tid * 131 + q) & 16383u];   // keep ds_adds observable
      }
    }
  }
  scr[(size_t)t * 1024 + tid] = sink + acc0[0] + acc0[3] + acc1[1] + acc2[2] + acc3[0];
}

// ---- fallback path (only if ws too small): correct but slow ----
__global__ __launch_bounds__(256) void k_bias_init(const float* __restrict__ bias,
                                                   float* __restrict__ out) {
  const int i = blockIdx.x * 256 + threadIdx.x;
  if (i < 64 * OUT_F) out[i] = bias[i & (OUT_F - 1)];
}

__global__ __launch_bounds__(256) void k_fallback(const int* __restrict__ rows,
                                                  const int* __restrict__ cols,
                                                  const float* __restrict__ vals,
                                                  const float* __restrict__ x,
                                                  float* __restrict__ out, int nnz) {
  const int gw = (int)(((u32)blockIdx.x * blockDim.x + threadIdx.x) >> 6);
  const int lane = threadIdx.x & 63;
  const int nw = (int)(((u32)gridDim.x * blockDim.x) >> 6);
  for (int i = gw; i < nnz; i += nw) {
    const int r = rows[i];
    const int c = cols[i];
    const float v = vals[i];
    const float xv = x[lane * IN_F + c];
    if (xv > THRESH) atomicAdd(&out[(size_t)lane * OUT_F + r], v * xv);
  }
}

extern "C" void kernel_launch(void* const* d_in, const int* in_sizes, int n_in,
                              void* d_out, int out_size, void* d_ws, size_t ws_size,
                              hipStream_t stream) {
  const float* x = (const float*)d_in[0];
  const int* rows = (const int*)d_in[1];
  const int* cols = (const int*)d_in[2];
  const float* vals = (const float*)d_in[3];
  const float* bias = (const float*)d_in[4];
  float* out = (float*)d_out;
  const int nnz = in_sizes[1];

  if (ws_size >= WS_NEEDED && nnz <= SBLOCKS * REC_PER_SB) {
    u16* xB = (u16*)((char*)d_ws + WS_XB);
    u32* gcursor = (u32*)((char*)d_ws + WS_CUR);
    u32* sortb = (u32*)((char*)d_ws + WS_BINS);
    float* scr = (float*)((char*)d_ws + WS_SCR);
    // real pipeline (round-11 champion, produces correct out)
    k_init<<<1, 256, 0, stream>>>(gcursor);
    k_scatter<<<SBLOCKS, 1024, 0, stream>>>(rows, cols, vals, (u32)nnz, x, xB,
                                            gcursor, sortb);
    k_accum<<<NBKT, 1024, 0, stream>>>(sortb, gcursor, xB, bias, out);
    // ablation probes (scratch only; read per-dispatch dur_us from rocprof)
    k_abl<0><<<NBKT, 1024, 0, stream>>>(sortb, gcursor, xB, scr);
    k_abl<1><<<NBKT, 1024, 0, stream>>>(sortb, gcursor, xB, scr);
    k_abl<2><<<NBKT, 1024, 0, stream>>>(sortb, gcursor, xB, scr);
    k_abl<3><<<NBKT, 1024, 0, stream>>>(sortb, gcursor, xB, scr);
  } else {
    k_bias_init<<<(64 * OUT_F + 255) / 256, 256, 0, stream>>>(bias, out);
    k_fallback<<<4096, 256, 0, stream>>>(rows, cols, vals, x, out, nnz);
  }
}

// Round 18
// 56.267 us; speedup vs baseline: 4.3979x; 4.3979x over previous
//
#include <hip/hip_runtime.h>
#include <hip/hip_bf16.h>
#include <stdint.h>

#define IN_F 4096
#define OUT_F 4096
#define NBKT 256
#define SBLOCKS 410          // 410 * 8192 = 3,358,720 >= NNZ
#define REC_PER_SB 8192
#define SMAX 14336u          // per-bucket cap: mean 13107, sigma 114, +10.8 sigma
#define THRESH 0.01f

typedef unsigned int u32;
typedef unsigned short u16;
typedef unsigned char u8;
typedef __attribute__((ext_vector_type(8))) short short8;   // 8 bf16 = 4 VGPR
typedef __attribute__((ext_vector_type(4))) float f32x4;

// ws layout — offsets DERIVED, 256B-padded
static constexpr size_t pad256(size_t x) { return (x + 255u) & ~(size_t)255u; }
static constexpr size_t WS_XB   = 0;                                           // u16 xB[512][64][8]
static constexpr size_t WS_CUR  = pad256(WS_XB + (size_t)512 * 64 * 8 * 2);    // u32 gcursor[256]
static constexpr size_t WS_BINS = pad256(WS_CUR + (size_t)NBKT * 4);           // u32 sortb[256][SMAX]
static constexpr size_t WS_NEEDED = WS_BINS + (size_t)NBKT * SMAX * 4;

static __device__ __forceinline__ u16 f2bf(float v) {
  __hip_bfloat16 h = __float2bfloat16(v);
  return *reinterpret_cast<u16*>(&h);
}

__global__ __launch_bounds__(256) void k_init(u32* __restrict__ gcursor) {
  gcursor[threadIdx.x] = 0u;
}

// r11-proven: fused [blocks 0..31: xB build] + per-block 256-bucket LDS counting
// sort of 8192 COO records + cursor-reserved bucket-major contiguous dump.
__global__ __launch_bounds__(1024) void k_scatter(const int* __restrict__ rows,
                                                  const int* __restrict__ cols,
                                                  const float* __restrict__ vals, u32 nnz,
                                                  const float* __restrict__ x,
                                                  u16* __restrict__ xB,
                                                  u32* __restrict__ gcursor,
                                                  u32* __restrict__ sortb) {
  __shared__ u32 cnt[NBKT];
  __shared__ u32 pref[NBKT + 1];
  __shared__ u32 gbase[NBKT];
  __shared__ u32 srt[REC_PER_SB];   // 32 KB
  __shared__ u8 srtb[REC_PER_SB];   // 8 KB
  const int tid = threadIdx.x;
  const int lane = tid & 63;
  const int wid = tid >> 6;

  if (blockIdx.x < 32) {
    const int g = blockIdx.x * 1024 + tid;
    const int b = g & 63;
    const int kg = g >> 6;
    const float* src = x + (size_t)b * IN_F + kg * 8;
    const f32x4 a0 = *reinterpret_cast<const f32x4*>(src);
    const f32x4 a1 = *reinterpret_cast<const f32x4*>(src + 4);
    short8 o;
#pragma unroll
    for (int e = 0; e < 4; ++e) {
      float v = a0[e]; v = (v > THRESH) ? v : 0.0f; o[e] = (short)f2bf(v);
    }
#pragma unroll
    for (int e = 0; e < 4; ++e) {
      float v = a1[e]; v = (v > THRESH) ? v : 0.0f; o[4 + e] = (short)f2bf(v);
    }
    *reinterpret_cast<short8*>(xB + ((size_t)kg * 64 + b) * 8) = o;
  }

  if (tid < NBKT) cnt[tid] = 0;
  __syncthreads();
  const u32 base_i = blockIdx.x * (u32)REC_PER_SB;
  u32 rec[8], bkt[8], rk[8];
#pragma unroll
  for (int j = 0; j < 8; ++j) {
    const u32 i = base_i + (u32)j * 1024u + tid;
    bkt[j] = 0xffffffffu;
    if (i < nnz) {
      const u32 r = (u32)rows[i] & 4095u;
      const u32 c = (u32)cols[i] & 4095u;
      rec[j] = (c << 20) | ((r & 15u) << 16) | (u32)f2bf(vals[i]);
      bkt[j] = r >> 4;
      rk[j] = atomicAdd(&cnt[bkt[j]], 1u);
    }
  }
  __syncthreads();
  if (wid == 0) {
    u32 a[4]; u32 s = 0;
#pragma unroll
    for (int j = 0; j < 4; ++j) { a[j] = cnt[lane * 4 + j]; s += a[j]; }
    u32 xx = s;
#pragma unroll
    for (int d = 1; d < 64; d <<= 1) {
      const u32 y = (u32)__shfl_up((int)xx, d, 64);
      if (lane >= d) xx += y;
    }
    u32 e = xx - s;
#pragma unroll
    for (int j = 0; j < 4; ++j) { pref[lane * 4 + j] = e; e += a[j]; }
    if (lane == 63) pref[NBKT] = e;
  }
  __syncthreads();
#pragma unroll
  for (int j = 0; j < 8; ++j)
    if (bkt[j] != 0xffffffffu) {
      const u32 pos = pref[bkt[j]] + rk[j];
      srt[pos] = rec[j];
      srtb[pos] = (u8)bkt[j];
    }
  if (tid < NBKT) {
    const u32 len = pref[tid + 1] - pref[tid];
    gbase[tid] = len ? atomicAdd(&gcursor[tid], len) : 0u;
  }
  __syncthreads();
  const u32 tot = pref[NBKT];
#pragma unroll
  for (int j = 0; j < 8; ++j) {
    const u32 i = (u32)j * 1024u + tid;
    if (i < tot) {
      const u32 t = srtb[i];
      const u32 off = gbase[t] + (i - pref[t]);
      if (off < SMAX) sortb[(size_t)t * SMAX + off] = srt[i];
    }
  }
}

// one block per bucket. SPILL FIX (r17 ablation: rec[14] preload at VGPR cap 64
// spilled to scratch -> ~60 MB hidden traffic = the whole 35us):
//  (a) no persistent record array — stream bin[i] per quarter (q2-4 hit L2);
//  (b) __launch_bounds__(1024,4): one 16-wave block/CU -> 128-VGPR budget.
__global__ __launch_bounds__(1024, 4) void k_accum(const u32* __restrict__ sortb,
                                                   const u32* __restrict__ ntot,
                                                   const u16* __restrict__ xB,
                                                   const float* __restrict__ bias,
                                                   float* __restrict__ out) {
  __shared__ float W[16 * 1024];    // 64 KB; reused as reduction scratch at the end
  const int tid = threadIdx.x;
  const int lane = tid & 63;
  const int w = tid >> 6;           // wave 0..15
  const u32 t = blockIdx.x;
  u32 n = ntot[t];
  if (n > SMAX) n = SMAX;
  const u32* bin = sortb + (size_t)t * SMAX;

  const f32x4 zv = {0.f, 0.f, 0.f, 0.f};
  f32x4 acc0 = zv, acc1 = zv, acc2 = zv, acc3 = zv;
  const int row = lane & 15;        // A-frag row / C col index
  const int e8 = (lane >> 4) * 8;   // A/B-frag k sub-offset

  for (int q = 0; q < 4; ++q) {
    __syncthreads();                // previous quarter's A-reads done before re-zero
#pragma unroll
    for (int j = 0; j < 4; ++j)
      *reinterpret_cast<f32x4*>(&W[j * 4096 + tid * 4]) = zv;
    __syncthreads();
    // direct streamed densify (native ds_add_f32; exact duplicate handling);
    // swizzle at 8-ELEMENT granularity: XOR bits >=3 only.
    for (u32 i = (u32)tid; i < n; i += 1024u) {
      const u32 rc = bin[i];
      if ((rc >> 30) == (u32)q) {
        const u32 rl = (rc >> 16) & 15u;
        const u32 cl = ((rc >> 20) & 1023u) ^ ((rl & 7u) << 3);
        unsafeAtomicAdd(&W[rl * 1024u + cl], __uint_as_float(rc << 16));
      }
    }
    __syncthreads();
    // dense MFMA over this quarter; wave w covers local k [w*64, w*64+64)
#pragma unroll
    for (int s = 0; s < 2; ++s) {
      const int klb = w * 64 + s * 32 + e8;                 // 8-aligned local k
      const int sw = klb ^ ((row & 7) << 3);                // matches write swizzle
      const f32x4 wa = *reinterpret_cast<const f32x4*>(&W[row * 1024 + sw]);
      const f32x4 wb = *reinterpret_cast<const f32x4*>(&W[row * 1024 + (sw + 4)]);
      short8 af;
#pragma unroll
      for (int e = 0; e < 4; ++e) af[e] = (short)f2bf(wa[e]);
#pragma unroll
      for (int e = 0; e < 4; ++e) af[4 + e] = (short)f2bf(wb[e]);
      const int kabs = q * 1024 + klb;
      const u16* bp = xB + (size_t)(kabs >> 3) * 512 + (u32)row * 8;
      const short8 b0 = *reinterpret_cast<const short8*>(bp);
      const short8 b1 = *reinterpret_cast<const short8*>(bp + 128);
      const short8 b2 = *reinterpret_cast<const short8*>(bp + 256);
      const short8 b3 = *reinterpret_cast<const short8*>(bp + 384);
      acc0 = __builtin_amdgcn_mfma_f32_16x16x32_bf16(af, b0, acc0, 0, 0, 0);
      acc1 = __builtin_amdgcn_mfma_f32_16x16x32_bf16(af, b1, acc1, 0, 0, 0);
      acc2 = __builtin_amdgcn_mfma_f32_16x16x32_bf16(af, b2, acc2, 0, 0, 0);
      acc3 = __builtin_amdgcn_mfma_f32_16x16x32_bf16(af, b3, acc3, 0, 0, 0);
    }
  }
  __syncthreads();
  // per-wave C partials: W[((w*4+g)*16 + crow)*16 + ccol]
  {
    const int ccol = lane & 15;                 // C col = lane&15 (m89-verified)
    const int rb = (lane >> 4) * 4;             // C row = (lane>>4)*4 + reg
#pragma unroll
    for (int qq = 0; qq < 4; ++qq) W[((w * 4 + 0) * 16 + rb + qq) * 16 + ccol] = acc0[qq];
#pragma unroll
    for (int qq = 0; qq < 4; ++qq) W[((w * 4 + 1) * 16 + rb + qq) * 16 + ccol] = acc1[qq];
#pragma unroll
    for (int qq = 0; qq < 4; ++qq) W[((w * 4 + 2) * 16 + rb + qq) * 16 + ccol] = acc2[qq];
#pragma unroll
    for (int qq = 0; qq < 4; ++qq) W[((w * 4 + 3) * 16 + rb + qq) * 16 + ccol] = acc3[qq];
  }
  __syncthreads();
  // reduce 16 wave-partials -> out(row rl, batch b); coalesced 64B store runs
  const int rl = tid & 15;
  const int b = tid >> 4;
  float sum = bias[t * 16u + rl];
#pragma unroll
  for (int w2 = 0; w2 < 16; ++w2)
    sum += W[((w2 * 4 + (b >> 4)) * 16 + rl) * 16 + (b & 15)];
  out[(size_t)b * OUT_F + t * 16u + rl] = sum;
}

// ---- fallback path (only if ws too small): correct but slow ----
__global__ __launch_bounds__(256) void k_bias_init(const float* __restrict__ bias,
                                                   float* __restrict__ out) {
  const int i = blockIdx.x * 256 + threadIdx.x;
  if (i < 64 * OUT_F) out[i] = bias[i & (OUT_F - 1)];
}

__global__ __launch_bounds__(256) void k_fallback(const int* __restrict__ rows,
                                                  const int* __restrict__ cols,
                                                  const float* __restrict__ vals,
                                                  const float* __restrict__ x,
                                                  float* __restrict__ out, int nnz) {
  const int gw = (int)(((u32)blockIdx.x * blockDim.x + threadIdx.x) >> 6);
  const int lane = threadIdx.x & 63;
  const int nw = (int)(((u32)gridDim.x * blockDim.x) >> 6);
  for (int i = gw; i < nnz; i += nw) {
    const int r = rows[i];
    const int c = cols[i];
    const float v = vals[i];
    const float xv = x[lane * IN_F + c];
    if (xv > THRESH) atomicAdd(&out[(size_t)lane * OUT_F + r], v * xv);
  }
}

extern "C" void kernel_launch(void* const* d_in, const int* in_sizes, int n_in,
                              void* d_out, int out_size, void* d_ws, size_t ws_size,
                              hipStream_t stream) {
  const float* x = (const float*)d_in[0];
  const int* rows = (const int*)d_in[1];
  const int* cols = (const int*)d_in[2];
  const float* vals = (const float*)d_in[3];
  const float* bias = (const float*)d_in[4];
  float* out = (float*)d_out;
  const int nnz = in_sizes[1];

  if (ws_size >= WS_NEEDED && nnz <= SBLOCKS * REC_PER_SB) {
    u16* xB = (u16*)((char*)d_ws + WS_XB);
    u32* gcursor = (u32*)((char*)d_ws + WS_CUR);
    u32* sortb = (u32*)((char*)d_ws + WS_BINS);
    k_init<<<1, 256, 0, stream>>>(gcursor);
    k_scatter<<<SBLOCKS, 1024, 0, stream>>>(rows, cols, vals, (u32)nnz, x, xB,
                                            gcursor, sortb);
    k_accum<<<NBKT, 1024, 0, stream>>>(sortb, gcursor, xB, bias, out);
  } else {
    k_bias_init<<<(64 * OUT_F + 255) / 256, 256, 0, stream>>>(bias, out);
    k_fallback<<<4096, 256, 0, stream>>>(rows, cols, vals, x, out, nnz);
  }
}